// Round 6
// baseline (262.992 us; speedup 1.0000x reference)
//
#include <hip/hip_runtime.h>
#include <hip/hip_bf16.h>

#define N_NODES 100000
#define D_IN 128
#define HID 256
#define D_OUT 64
#define TR 32

typedef __attribute__((ext_vector_type(8))) short bf8;
typedef __attribute__((ext_vector_type(4))) float f4;

static __device__ __forceinline__ unsigned short f2bf(float f) {
    __hip_bfloat16 h = __float2bfloat16(f);
    return *reinterpret_cast<unsigned short*>(&h);
}
static __device__ __forceinline__ float bflo(unsigned int u) { return __uint_as_float(u << 16); }
static __device__ __forceinline__ float bfhi(unsigned int u) { return __uint_as_float(u & 0xffff0000u); }
static __device__ __forceinline__ float bfs(unsigned short u) {
    return __uint_as_float((unsigned int)u << 16);
}

// ---------------- fused prep: cvt_x | cvt_w1 | cvt_w2 | zero(cnt) ----------------
// block ranges: [0,12500) cvt_x, [12500,12628) W1t, [12628,12692) W2t, [12692,13083) zero

__global__ __launch_bounds__(256) void k_prep(const float* __restrict__ x,
                                              unsigned long long* __restrict__ xb,
                                              const float* __restrict__ W1,
                                              unsigned short* __restrict__ W1t,
                                              const float* __restrict__ W2,
                                              unsigned short* __restrict__ W2t,
                                              int* __restrict__ cnt) {
    int b = blockIdx.x, t = threadIdx.x;
    if (b < 12500) {
        int i = b * 256 + t;  // float4 index over x
        float4 v = ((const float4*)x)[i];
        unsigned long long o = (unsigned long long)f2bf(v.x) |
                               ((unsigned long long)f2bf(v.y) << 16) |
                               ((unsigned long long)f2bf(v.z) << 32) |
                               ((unsigned long long)f2bf(v.w) << 48);
        xb[i] = o;
    } else if (b < 12628) {
        int i = (b - 12500) * 256 + t;  // 32768 elems
        int n = i >> 7, k = i & 127;
        W1t[i] = f2bf(W1[k * HID + n]);
    } else if (b < 12692) {
        int i = (b - 12628) * 256 + t;  // 16384 elems
        int n = i >> 8, k = i & 255;
        W2t[i] = f2bf(W2[k * D_OUT + n]);
    } else {
        int i = (b - 12692) * 256 + t;
        if (i < N_NODES) cnt[i] = 0;
    }
}

// ---------------- CSR build ----------------

__global__ void k_count(const int* __restrict__ dst, int E, int* __restrict__ cnt) {
    int e = blockIdx.x * blockDim.x + threadIdx.x;
    if (e < E) atomicAdd(&cnt[dst[e]], 1);
}

// per-block exclusive prefix into row_ptr, block totals into bsum; dinv fused
__global__ __launch_bounds__(256) void k_scan_part(const int* __restrict__ cnt,
                                                   int* __restrict__ row_ptr,
                                                   int* __restrict__ bsum,
                                                   float* __restrict__ dinv, int n) {
    __shared__ int s[256];
    int t = threadIdx.x, i = blockIdx.x * 256 + t;
    int v = (i < n) ? cnt[i] : 0;
    s[t] = v;
    __syncthreads();
    for (int off = 1; off < 256; off <<= 1) {
        int u = (t >= off) ? s[t - off] : 0;
        __syncthreads();
        s[t] += u;
        __syncthreads();
    }
    if (i < n) {
        row_ptr[i] = s[t] - v;  // exclusive within block
        dinv[i] = rsqrtf((float)v + 1.0f);  // +1 self-loop
    }
    if (t == 255) bsum[blockIdx.x] = s[255];
}

// single block: exclusive-scan bsum in place; write row_ptr[n] = grand total
__global__ __launch_bounds__(512) void k_scan_base(int* __restrict__ bsum,
                                                   int* __restrict__ row_ptr, int nb, int n) {
    __shared__ int s[512];
    int t = threadIdx.x;
    int v = (t < nb) ? bsum[t] : 0;
    s[t] = v;
    __syncthreads();
    for (int off = 1; off < 512; off <<= 1) {
        int u = (t >= off) ? s[t - off] : 0;
        __syncthreads();
        s[t] += u;
        __syncthreads();
    }
    if (t < nb) bsum[t] = s[t] - v;  // exclusive base
    if (t == 511) row_ptr[n] = s[511];
}

// add block bases; final row_ptr and cursor (cursor aliases cnt — counts are dead)
__global__ void k_scan_fin(int* __restrict__ row_ptr, const int* __restrict__ bsum,
                           int* __restrict__ cursor, int n) {
    int i = blockIdx.x * blockDim.x + threadIdx.x;
    if (i >= n) return;
    int v = row_ptr[i] + bsum[i >> 8];
    row_ptr[i] = v;
    cursor[i] = v;
}

// col-only scatter: 4 B per edge (weights recomputed in the pulls)
__global__ void k_fill(const int* __restrict__ src, const int* __restrict__ dst, int E,
                       int* __restrict__ cursor, int* __restrict__ col) {
    int e = blockIdx.x * blockDim.x + threadIdx.x;
    if (e >= E) return;
    int s = src[e], d = dst[e];
    int pos = atomicAdd(&cursor[d], 1);
    col[pos] = s;
}

// ---------------- layer-1 pull: agg = A_norm @ x, bf16 in / bf16 out ----------------
// one wave per node; lane holds cols {2*lane, 2*lane+1} packed bf16x2
// weight folding: agg_row = di * ( di*x[wid] + sum_e dinv[col[e]] * x[col[e]] )

__global__ __launch_bounds__(256) void k_pull1(const int* __restrict__ row_ptr,
                                               const int* __restrict__ col,
                                               const unsigned int* __restrict__ xb,
                                               const float* __restrict__ dinv,
                                               unsigned int* __restrict__ agg) {
    int wid = (blockIdx.x * blockDim.x + threadIdx.x) >> 6;
    int lane = threadIdx.x & 63;
    if (wid >= N_NODES) return;
    int beg = row_ptr[wid], end = row_ptr[wid + 1];
    float di = dinv[wid];
    unsigned int u = xb[(size_t)wid * 64 + lane];
    float ax = di * bflo(u), ay = di * bfhi(u);
    int e = beg;
    for (; e + 8 <= end; e += 8) {
        int s0 = col[e + 0], s1 = col[e + 1], s2 = col[e + 2], s3 = col[e + 3];
        int s4 = col[e + 4], s5 = col[e + 5], s6 = col[e + 6], s7 = col[e + 7];
        unsigned int u0 = xb[(size_t)s0 * 64 + lane];
        unsigned int u1 = xb[(size_t)s1 * 64 + lane];
        unsigned int u2 = xb[(size_t)s2 * 64 + lane];
        unsigned int u3 = xb[(size_t)s3 * 64 + lane];
        unsigned int u4 = xb[(size_t)s4 * 64 + lane];
        unsigned int u5 = xb[(size_t)s5 * 64 + lane];
        unsigned int u6 = xb[(size_t)s6 * 64 + lane];
        unsigned int u7 = xb[(size_t)s7 * 64 + lane];
        float w0 = dinv[s0], w1 = dinv[s1], w2 = dinv[s2], w3 = dinv[s3];
        float w4 = dinv[s4], w5 = dinv[s5], w6 = dinv[s6], w7 = dinv[s7];
        ax += w0 * bflo(u0); ay += w0 * bfhi(u0);
        ax += w1 * bflo(u1); ay += w1 * bfhi(u1);
        ax += w2 * bflo(u2); ay += w2 * bfhi(u2);
        ax += w3 * bflo(u3); ay += w3 * bfhi(u3);
        ax += w4 * bflo(u4); ay += w4 * bfhi(u4);
        ax += w5 * bflo(u5); ay += w5 * bfhi(u5);
        ax += w6 * bflo(u6); ay += w6 * bfhi(u6);
        ax += w7 * bflo(u7); ay += w7 * bfhi(u7);
    }
    for (; e < end; e++) {
        int s = col[e];
        float w = dinv[s];
        unsigned int uu = xb[(size_t)s * 64 + lane];
        ax += w * bflo(uu);
        ay += w * bfhi(uu);
    }
    ax *= di;
    ay *= di;
    unsigned int o = (unsigned int)f2bf(ax) | ((unsigned int)f2bf(ay) << 16);
    agg[(size_t)wid * 64 + lane] = o;
}

// ---------------- fused GEMM chain (MFMA): m = relu(agg@W1+b1)@W2, bf16 out ----------------
// m (64 bf16 = 128 B/row) written IN PLACE into the first half of each agg row
// (agg row = 256 B, stride kept at 128 ushorts). Block b writes only rows it
// staged to LDS before the first barrier -> no cross-block hazard.

__global__ __launch_bounds__(256) void k_fused_mfma(unsigned short* __restrict__ agg,
                                                    const unsigned short* __restrict__ W1t,
                                                    const float* __restrict__ b1,
                                                    const unsigned short* __restrict__ W2t) {
    __shared__ char sA[TR * D_IN * 2];  // 8 KB, row stride 256B
    __shared__ char sH[TR * HID * 2];   // 16 KB, row stride 512B
    int t = threadIdx.x, wave = t >> 6, lane = t & 63;
    int lr = lane & 15, lg = lane >> 4;
    size_t row0 = (size_t)blockIdx.x * TR;

    // stage A tile: 512 x 16B chunks, XOR swizzle byte ^= (row&7)<<4
    {
        const float4* g = (const float4*)(agg + row0 * D_IN);
#pragma unroll
        for (int c0 = 0; c0 < 2; c0++) {
            int c = c0 * 256 + t;
            int row = c >> 4;
            *(float4*)(sA + ((c * 16) ^ ((row & 7) << 4))) = g[c];
        }
    }
    __syncthreads();

    // GEMM1: wave covers cols wave*64 .. wave*64+63 (4 tiles), both 16-row halves
    f4 acc1[4][2];
#pragma unroll
    for (int tt = 0; tt < 4; tt++)
#pragma unroll
        for (int h = 0; h < 2; h++) acc1[tt][h] = (f4){0.f, 0.f, 0.f, 0.f};

#pragma unroll
    for (int kk = 0; kk < 4; kk++) {
        bf8 a0 = *(const bf8*)(sA + ((lr * 256 + kk * 64 + lg * 16) ^ ((lr & 7) << 4)));
        bf8 a1 = *(const bf8*)(sA + (((16 + lr) * 256 + kk * 64 + lg * 16) ^ (((16 + lr) & 7) << 4)));
#pragma unroll
        for (int tt = 0; tt < 4; tt++) {
            bf8 b = *(const bf8*)(W1t + (size_t)(wave * 64 + tt * 16 + lr) * D_IN + kk * 32 + lg * 8);
            acc1[tt][0] = __builtin_amdgcn_mfma_f32_16x16x32_bf16(a0, b, acc1[tt][0], 0, 0, 0);
            acc1[tt][1] = __builtin_amdgcn_mfma_f32_16x16x32_bf16(a1, b, acc1[tt][1], 0, 0, 0);
        }
    }

    // epilogue 1: bias + relu + cvt bf16 -> sH
#pragma unroll
    for (int tt = 0; tt < 4; tt++) {
        int colc = wave * 64 + tt * 16 + lr;
        float bias = b1[colc];
#pragma unroll
        for (int h = 0; h < 2; h++) {
#pragma unroll
            for (int ri = 0; ri < 4; ri++) {
                int row = h * 16 + lg * 4 + ri;
                float hv = acc1[tt][h][ri] + bias;
                hv = hv > 0.f ? hv : 0.f;
                *(unsigned short*)(sH + ((row * 512 + colc * 2) ^ ((row & 7) << 4))) = f2bf(hv);
            }
        }
    }
    __syncthreads();

    // GEMM2: wave covers cols wave*16 .. wave*16+15, K=256
    f4 acc2[2];
    acc2[0] = (f4){0.f, 0.f, 0.f, 0.f};
    acc2[1] = (f4){0.f, 0.f, 0.f, 0.f};
#pragma unroll
    for (int kk = 0; kk < 8; kk++) {
        bf8 a0 = *(const bf8*)(sH + ((lr * 512 + kk * 64 + lg * 16) ^ ((lr & 7) << 4)));
        bf8 a1 = *(const bf8*)(sH + (((16 + lr) * 512 + kk * 64 + lg * 16) ^ (((16 + lr) & 7) << 4)));
        bf8 b = *(const bf8*)(W2t + (size_t)(wave * 16 + lr) * HID + kk * 32 + lg * 8);
        acc2[0] = __builtin_amdgcn_mfma_f32_16x16x32_bf16(a0, b, acc2[0], 0, 0, 0);
        acc2[1] = __builtin_amdgcn_mfma_f32_16x16x32_bf16(a1, b, acc2[1], 0, 0, 0);
    }
    // write m (bf16) into first 64 ushorts of each owned agg row (stride 128)
    int colc = wave * 16 + lr;
#pragma unroll
    for (int h = 0; h < 2; h++)
#pragma unroll
        for (int ri = 0; ri < 4; ri++) {
            int row = h * 16 + lg * 4 + ri;
            agg[(row0 + row) * 128 + colc] = f2bf(acc2[h][ri]);
        }
}

// ---------------- layer-2 pull: out = A_norm @ m + b2 (bf16 gather, fp32 out) ----------------
// m rows: 64 bf16 at stride 128 ushorts inside the agg buffer; weight folding as pull1

__global__ __launch_bounds__(256) void k_pull2(const int* __restrict__ row_ptr,
                                               const int* __restrict__ col,
                                               const unsigned short* __restrict__ m,
                                               const float* __restrict__ dinv,
                                               const float* __restrict__ b2,
                                               float* __restrict__ out) {
    int wid = (blockIdx.x * blockDim.x + threadIdx.x) >> 6;
    int lane = threadIdx.x & 63;
    if (wid >= N_NODES) return;
    int beg = row_ptr[wid], end = row_ptr[wid + 1];
    float di = dinv[wid];
    float acc = di * bfs(m[(size_t)wid * 128 + lane]);
    int e = beg;
    for (; e + 8 <= end; e += 8) {
        int s0 = col[e + 0], s1 = col[e + 1], s2 = col[e + 2], s3 = col[e + 3];
        int s4 = col[e + 4], s5 = col[e + 5], s6 = col[e + 6], s7 = col[e + 7];
        float v0 = bfs(m[(size_t)s0 * 128 + lane]);
        float v1 = bfs(m[(size_t)s1 * 128 + lane]);
        float v2 = bfs(m[(size_t)s2 * 128 + lane]);
        float v3 = bfs(m[(size_t)s3 * 128 + lane]);
        float v4 = bfs(m[(size_t)s4 * 128 + lane]);
        float v5 = bfs(m[(size_t)s5 * 128 + lane]);
        float v6 = bfs(m[(size_t)s6 * 128 + lane]);
        float v7 = bfs(m[(size_t)s7 * 128 + lane]);
        acc += dinv[s0] * v0;
        acc += dinv[s1] * v1;
        acc += dinv[s2] * v2;
        acc += dinv[s3] * v3;
        acc += dinv[s4] * v4;
        acc += dinv[s5] * v5;
        acc += dinv[s6] * v6;
        acc += dinv[s7] * v7;
    }
    for (; e < end; e++) {
        int s = col[e];
        acc += dinv[s] * bfs(m[(size_t)s * 128 + lane]);
    }
    out[(size_t)wid * D_OUT + lane] = di * acc + b2[lane];
}

// ---------------- launch ----------------

extern "C" void kernel_launch(void* const* d_in, const int* in_sizes, int n_in,
                              void* d_out, int out_size, void* d_ws, size_t ws_size,
                              hipStream_t stream) {
    const float* x  = (const float*)d_in[0];
    const int*   ei = (const int*)d_in[1];
    const float* W1 = (const float*)d_in[2];
    const float* b1 = (const float*)d_in[3];
    const float* W2 = (const float*)d_in[4];
    const float* b2 = (const float*)d_in[5];
    float* out = (float*)d_out;

    const int E = in_sizes[1] / 2;
    const int* src = ei;
    const int* dst = ei + E;

    // workspace layout — total < 59.2 MB proven-good footprint
    char* ws = (char*)d_ws;
    int* cnt            = (int*)(ws + 0);          // 100096 ints (+bsum tail)
    int* bsum           = cnt + 100096;            // 391 ints
    int* row_ptr        = (int*)(ws + 402176);     // 100096 ints
    int* col            = (int*)(ws + 802560);     // 800000 ints (3.2 MB)
    float* dinv         = (float*)(ws + 4002560);  // 100096 f
    unsigned short* W1t = (unsigned short*)(ws + 4402944);   // 256*128 bf16
    unsigned short* W2t = (unsigned short*)(ws + 4468480);   // 64*256 bf16
    unsigned short* xb  = (unsigned short*)(ws + 4501248);   // N*128 bf16 (25.6 MB)
    unsigned short* aggb = (unsigned short*)(ws + 30101248); // N*128 bf16 (25.6 MB), m in place

    const int NB = (N_NODES + 255) / 256;  // 391

    // fused prep: cvt_x | cvt_w1 | cvt_w2 | zero(cnt)
    k_prep<<<13083, 256, 0, stream>>>(x, (unsigned long long*)xb, W1, W1t, W2, W2t, cnt);

    // CSR build (dinv fused into scan_part)
    k_count<<<(E + 255) / 256, 256, 0, stream>>>(dst, E, cnt);
    k_scan_part<<<NB, 256, 0, stream>>>(cnt, row_ptr, bsum, dinv, N_NODES);
    k_scan_base<<<1, 512, 0, stream>>>(bsum, row_ptr, NB, N_NODES);
    k_scan_fin<<<NB, 256, 0, stream>>>(row_ptr, bsum, cnt, N_NODES);  // cursor -> cnt
    k_fill<<<(E + 255) / 256, 256, 0, stream>>>(src, dst, E, cnt, col);

    // layer-1 pull (bf16 gather, 128 dims, folded weights)
    k_pull1<<<(N_NODES * 64 + 255) / 256, 256, 0, stream>>>(row_ptr, col,
                                                            (const unsigned int*)xb, dinv,
                                                            (unsigned int*)aggb);

    // fused MFMA GEMM chain -> m (bf16, in place over aggb)
    k_fused_mfma<<<N_NODES / TR, 256, 0, stream>>>(aggb, W1t, b1, W2t);

    // layer-2 pull (64 dims, bf16 gather, folded weights) + bias
    k_pull2<<<(N_NODES * 64 + 255) / 256, 256, 0, stream>>>(row_ptr, col, aggb, dinv, b2, out);
}

// Round 7
// 216.142 us; speedup vs baseline: 1.2168x; 1.2168x over previous
//
#include <hip/hip_runtime.h>
#include <hip/hip_bf16.h>

#define N_NODES 100000
#define D_IN 128
#define HID 256
#define D_OUT 64
#define TR 32
#define NBUK 196   // dst>>9 buckets of 512 nodes
#define BSH 9

typedef __attribute__((ext_vector_type(8))) short bf8;
typedef __attribute__((ext_vector_type(4))) float f4;

static __device__ __forceinline__ unsigned short f2bf(float f) {
    __hip_bfloat16 h = __float2bfloat16(f);
    return *reinterpret_cast<unsigned short*>(&h);
}
static __device__ __forceinline__ float bflo(unsigned int u) { return __uint_as_float(u << 16); }
static __device__ __forceinline__ float bfhi(unsigned int u) { return __uint_as_float(u & 0xffff0000u); }
static __device__ __forceinline__ float bfs(unsigned short u) {
    return __uint_as_float((unsigned int)u << 16);
}

// ---------------- fused prep: cvt_x | cvt_w1 | cvt_w2 | zero(bhist) ----------------
// blocks: [0,12500) cvt_x, [12500,12628) W1t, [12628,12692) W2t, 12692 zero bhist

__global__ __launch_bounds__(256) void k_prep(const float* __restrict__ x,
                                              unsigned long long* __restrict__ xb,
                                              const float* __restrict__ W1,
                                              unsigned short* __restrict__ W1t,
                                              const float* __restrict__ W2,
                                              unsigned short* __restrict__ W2t,
                                              int* __restrict__ bhist) {
    int b = blockIdx.x, t = threadIdx.x;
    if (b < 12500) {
        int i = b * 256 + t;  // float4 index over x
        float4 v = ((const float4*)x)[i];
        unsigned long long o = (unsigned long long)f2bf(v.x) |
                               ((unsigned long long)f2bf(v.y) << 16) |
                               ((unsigned long long)f2bf(v.z) << 32) |
                               ((unsigned long long)f2bf(v.w) << 48);
        xb[i] = o;
    } else if (b < 12628) {
        int i = (b - 12500) * 256 + t;
        int n = i >> 7, k = i & 127;
        W1t[i] = f2bf(W1[k * HID + n]);
    } else if (b < 12692) {
        int i = (b - 12628) * 256 + t;
        int n = i >> 8, k = i & 255;
        W2t[i] = f2bf(W2[k * D_OUT + n]);
    } else {
        if (t < NBUK) bhist[t] = 0;
    }
}

// ---------------- bucketed CSR build ----------------

// per-block LDS histogram of dst buckets -> 196 global atomics per block
__global__ __launch_bounds__(256) void k_hist(const int* __restrict__ dst, int E,
                                              int* __restrict__ bhist) {
    __shared__ int h[NBUK];
    int t = threadIdx.x;
    if (t < NBUK) h[t] = 0;
    __syncthreads();
    int base = blockIdx.x * 4096;
    for (int j = 0; j < 16; j++) {
        int e = base + j * 256 + t;
        if (e < E) atomicAdd(&h[dst[e] >> BSH], 1);
    }
    __syncthreads();
    if (t < NBUK && h[t] > 0) atomicAdd(&bhist[t], h[t]);
}

// single block: exclusive scan of 196 bucket counts -> bbase (and cursor copy)
__global__ __launch_bounds__(256) void k_scanB(const int* __restrict__ bhist,
                                               int* __restrict__ bbase,
                                               int* __restrict__ bcursor) {
    __shared__ int s[256];
    int t = threadIdx.x;
    int v = (t < NBUK) ? bhist[t] : 0;
    s[t] = v;
    __syncthreads();
    for (int off = 1; off < 256; off <<= 1) {
        int u = (t >= off) ? s[t - off] : 0;
        __syncthreads();
        s[t] += u;
        __syncthreads();
    }
    if (t < NBUK) {
        bbase[t] = s[t] - v;
        bcursor[t] = s[t] - v;
    }
    if (t == NBUK - 1) bbase[NBUK] = s[t];
}

// bin edges by bucket: edges cached in regs, LDS rank, per-block runs -> L2-coalesced stores
// record = (dst&511)<<17 | src   (src < 2^17)
__global__ __launch_bounds__(256) void k_bin(const int* __restrict__ src,
                                             const int* __restrict__ dst, int E,
                                             int* __restrict__ bcursor,
                                             unsigned int* __restrict__ bin) {
    __shared__ int histL[NBUK], baseL[NBUK], rankL[NBUK];
    int t = threadIdx.x;
    if (t < NBUK) {
        histL[t] = 0;
        rankL[t] = 0;
    }
    __syncthreads();
    int base = blockIdx.x * 4096;
    int ss[16], dd[16];
#pragma unroll
    for (int j = 0; j < 16; j++) {
        int e = base + j * 256 + t;
        if (e < E) {
            ss[j] = src[e];
            dd[j] = dst[e];
            atomicAdd(&histL[dd[j] >> BSH], 1);
        } else {
            dd[j] = -1;
        }
    }
    __syncthreads();
    if (t < NBUK && histL[t] > 0) baseL[t] = atomicAdd(&bcursor[t], histL[t]);
    __syncthreads();
#pragma unroll
    for (int j = 0; j < 16; j++) {
        if (dd[j] >= 0) {
            int bu = dd[j] >> BSH;
            int r = atomicAdd(&rankL[bu], 1);
            bin[baseL[bu] + r] = ((unsigned int)(dd[j] & 511) << 17) | (unsigned int)ss[j];
        }
    }
}

// per-bucket node counts via LDS atomics; coalesced cnt writes (replaces global k_count)
__global__ __launch_bounds__(256) void k_cnt(const unsigned int* __restrict__ bin,
                                             const int* __restrict__ bbase,
                                             int* __restrict__ cnt) {
    __shared__ int c[512];
    int b = blockIdx.x, t = threadIdx.x;
    c[t] = 0;
    c[t + 256] = 0;
    __syncthreads();
    int lo = bbase[b], hi = bbase[b + 1];
    for (int e = lo + t; e < hi; e += 256) atomicAdd(&c[bin[e] >> 17], 1);
    __syncthreads();
    int node0 = b << BSH;
    int nbn = N_NODES - node0;
    if (nbn > 512) nbn = 512;
    if (t < nbn) cnt[node0 + t] = c[t];
    if (t + 256 < nbn) cnt[node0 + t + 256] = c[t + 256];
}

// per-block exclusive prefix into row_ptr, block totals into bsum; dinv fused
__global__ __launch_bounds__(256) void k_scan_part(const int* __restrict__ cnt,
                                                   int* __restrict__ row_ptr,
                                                   int* __restrict__ bsum,
                                                   float* __restrict__ dinv, int n) {
    __shared__ int s[256];
    int t = threadIdx.x, i = blockIdx.x * 256 + t;
    int v = (i < n) ? cnt[i] : 0;
    s[t] = v;
    __syncthreads();
    for (int off = 1; off < 256; off <<= 1) {
        int u = (t >= off) ? s[t - off] : 0;
        __syncthreads();
        s[t] += u;
        __syncthreads();
    }
    if (i < n) {
        row_ptr[i] = s[t] - v;
        dinv[i] = rsqrtf((float)v + 1.0f);  // +1 self-loop
    }
    if (t == 255) bsum[blockIdx.x] = s[255];
}

__global__ __launch_bounds__(512) void k_scan_base(int* __restrict__ bsum,
                                                   int* __restrict__ row_ptr, int nb, int n) {
    __shared__ int s[512];
    int t = threadIdx.x;
    int v = (t < nb) ? bsum[t] : 0;
    s[t] = v;
    __syncthreads();
    for (int off = 1; off < 512; off <<= 1) {
        int u = (t >= off) ? s[t - off] : 0;
        __syncthreads();
        s[t] += u;
        __syncthreads();
    }
    if (t < nb) bsum[t] = s[t] - v;
    if (t == 511) row_ptr[n] = s[511];
}

__global__ void k_scan_fin(int* __restrict__ row_ptr, const int* __restrict__ bsum, int n) {
    int i = blockIdx.x * blockDim.x + threadIdx.x;
    if (i < n) row_ptr[i] += bsum[i >> 8];
}

// per-bucket final placement: cursors + dst-dinv in LDS, stores into bucket's CSR region
__global__ __launch_bounds__(256) void k_place(const unsigned int* __restrict__ bin,
                                               const int* __restrict__ bbase,
                                               const int* __restrict__ row_ptr,
                                               const float* __restrict__ dinv,
                                               int2* __restrict__ cw) {
    __shared__ int cur[512];
    __shared__ float dl[512];
    int b = blockIdx.x, t = threadIdx.x;
    int node0 = b << BSH;
    int nbn = N_NODES - node0;
    if (nbn > 512) nbn = 512;
    if (t < nbn) {
        cur[t] = row_ptr[node0 + t];
        dl[t] = dinv[node0 + t];
    }
    if (t + 256 < nbn) {
        cur[t + 256] = row_ptr[node0 + t + 256];
        dl[t + 256] = dinv[node0 + t + 256];
    }
    __syncthreads();
    int lo = bbase[b], hi = bbase[b + 1];
    for (int e = lo + t; e < hi; e += 256) {
        unsigned int rec = bin[e];
        int s = rec & 0x1FFFF;
        int dloc = rec >> 17;
        int pos = atomicAdd(&cur[dloc], 1);
        int2 v;
        v.x = s;
        v.y = __float_as_int(dinv[s] * dl[dloc]);
        cw[pos] = v;
    }
}

// ---------------- layer-1 pull: agg = A_norm @ x, bf16 in / bf16 out ----------------

__global__ __launch_bounds__(256) void k_pull1(const int* __restrict__ row_ptr,
                                               const int2* __restrict__ cw,
                                               const unsigned int* __restrict__ xb,
                                               const float* __restrict__ dinv,
                                               unsigned int* __restrict__ agg) {
    int wid = (blockIdx.x * blockDim.x + threadIdx.x) >> 6;
    int lane = threadIdx.x & 63;
    if (wid >= N_NODES) return;
    int beg = row_ptr[wid], end = row_ptr[wid + 1];
    float di = dinv[wid];
    float w0 = di * di;
    unsigned int u = xb[(size_t)wid * 64 + lane];
    float ax = w0 * bflo(u), ay = w0 * bfhi(u);
    int e = beg;
    for (; e + 8 <= end; e += 8) {
        int2 c0 = cw[e + 0], c1 = cw[e + 1], c2 = cw[e + 2], c3 = cw[e + 3];
        int2 c4 = cw[e + 4], c5 = cw[e + 5], c6 = cw[e + 6], c7 = cw[e + 7];
        unsigned int u0 = xb[(size_t)c0.x * 64 + lane];
        unsigned int u1 = xb[(size_t)c1.x * 64 + lane];
        unsigned int u2 = xb[(size_t)c2.x * 64 + lane];
        unsigned int u3 = xb[(size_t)c3.x * 64 + lane];
        unsigned int u4 = xb[(size_t)c4.x * 64 + lane];
        unsigned int u5 = xb[(size_t)c5.x * 64 + lane];
        unsigned int u6 = xb[(size_t)c6.x * 64 + lane];
        unsigned int u7 = xb[(size_t)c7.x * 64 + lane];
        float w_0 = __int_as_float(c0.y), w_1 = __int_as_float(c1.y);
        float w_2 = __int_as_float(c2.y), w_3 = __int_as_float(c3.y);
        float w_4 = __int_as_float(c4.y), w_5 = __int_as_float(c5.y);
        float w_6 = __int_as_float(c6.y), w_7 = __int_as_float(c7.y);
        ax += w_0 * bflo(u0); ay += w_0 * bfhi(u0);
        ax += w_1 * bflo(u1); ay += w_1 * bfhi(u1);
        ax += w_2 * bflo(u2); ay += w_2 * bfhi(u2);
        ax += w_3 * bflo(u3); ay += w_3 * bfhi(u3);
        ax += w_4 * bflo(u4); ay += w_4 * bfhi(u4);
        ax += w_5 * bflo(u5); ay += w_5 * bfhi(u5);
        ax += w_6 * bflo(u6); ay += w_6 * bfhi(u6);
        ax += w_7 * bflo(u7); ay += w_7 * bfhi(u7);
    }
    for (; e < end; e++) {
        int2 c = cw[e];
        float w = __int_as_float(c.y);
        unsigned int uu = xb[(size_t)c.x * 64 + lane];
        ax += w * bflo(uu);
        ay += w * bfhi(uu);
    }
    unsigned int o = (unsigned int)f2bf(ax) | ((unsigned int)f2bf(ay) << 16);
    agg[(size_t)wid * 64 + lane] = o;
}

// ---------------- fused GEMM chain (MFMA): m = relu(agg@W1+b1)@W2, bf16 out ----------------
// m (64 bf16/row) written IN PLACE into first half of each agg row (stride 128 ushorts).

__global__ __launch_bounds__(256) void k_fused_mfma(unsigned short* __restrict__ agg,
                                                    const unsigned short* __restrict__ W1t,
                                                    const float* __restrict__ b1,
                                                    const unsigned short* __restrict__ W2t) {
    __shared__ char sA[TR * D_IN * 2];  // 8 KB, row stride 256B
    __shared__ char sH[TR * HID * 2];   // 16 KB, row stride 512B
    int t = threadIdx.x, wave = t >> 6, lane = t & 63;
    int lr = lane & 15, lg = lane >> 4;
    size_t row0 = (size_t)blockIdx.x * TR;

    {
        const float4* g = (const float4*)(agg + row0 * D_IN);
#pragma unroll
        for (int c0 = 0; c0 < 2; c0++) {
            int c = c0 * 256 + t;
            int row = c >> 4;
            *(float4*)(sA + ((c * 16) ^ ((row & 7) << 4))) = g[c];
        }
    }
    __syncthreads();

    f4 acc1[4][2];
#pragma unroll
    for (int tt = 0; tt < 4; tt++)
#pragma unroll
        for (int h = 0; h < 2; h++) acc1[tt][h] = (f4){0.f, 0.f, 0.f, 0.f};

#pragma unroll
    for (int kk = 0; kk < 4; kk++) {
        bf8 a0 = *(const bf8*)(sA + ((lr * 256 + kk * 64 + lg * 16) ^ ((lr & 7) << 4)));
        bf8 a1 = *(const bf8*)(sA + (((16 + lr) * 256 + kk * 64 + lg * 16) ^ (((16 + lr) & 7) << 4)));
#pragma unroll
        for (int tt = 0; tt < 4; tt++) {
            bf8 b = *(const bf8*)(W1t + (size_t)(wave * 64 + tt * 16 + lr) * D_IN + kk * 32 + lg * 8);
            acc1[tt][0] = __builtin_amdgcn_mfma_f32_16x16x32_bf16(a0, b, acc1[tt][0], 0, 0, 0);
            acc1[tt][1] = __builtin_amdgcn_mfma_f32_16x16x32_bf16(a1, b, acc1[tt][1], 0, 0, 0);
        }
    }

#pragma unroll
    for (int tt = 0; tt < 4; tt++) {
        int colc = wave * 64 + tt * 16 + lr;
        float bias = b1[colc];
#pragma unroll
        for (int h = 0; h < 2; h++) {
#pragma unroll
            for (int ri = 0; ri < 4; ri++) {
                int row = h * 16 + lg * 4 + ri;
                float hv = acc1[tt][h][ri] + bias;
                hv = hv > 0.f ? hv : 0.f;
                *(unsigned short*)(sH + ((row * 512 + colc * 2) ^ ((row & 7) << 4))) = f2bf(hv);
            }
        }
    }
    __syncthreads();

    f4 acc2[2];
    acc2[0] = (f4){0.f, 0.f, 0.f, 0.f};
    acc2[1] = (f4){0.f, 0.f, 0.f, 0.f};
#pragma unroll
    for (int kk = 0; kk < 8; kk++) {
        bf8 a0 = *(const bf8*)(sH + ((lr * 512 + kk * 64 + lg * 16) ^ ((lr & 7) << 4)));
        bf8 a1 = *(const bf8*)(sH + (((16 + lr) * 512 + kk * 64 + lg * 16) ^ (((16 + lr) & 7) << 4)));
        bf8 b = *(const bf8*)(W2t + (size_t)(wave * 16 + lr) * HID + kk * 32 + lg * 8);
        acc2[0] = __builtin_amdgcn_mfma_f32_16x16x32_bf16(a0, b, acc2[0], 0, 0, 0);
        acc2[1] = __builtin_amdgcn_mfma_f32_16x16x32_bf16(a1, b, acc2[1], 0, 0, 0);
    }
    int colc = wave * 16 + lr;
#pragma unroll
    for (int h = 0; h < 2; h++)
#pragma unroll
        for (int ri = 0; ri < 4; ri++) {
            int row = h * 16 + lg * 4 + ri;
            agg[(row0 + row) * 128 + colc] = f2bf(acc2[h][ri]);
        }
}

// ---------------- layer-2 pull: out = A_norm @ m + b2 (bf16 gather, fp32 out) ----------------

__global__ __launch_bounds__(256) void k_pull2(const int* __restrict__ row_ptr,
                                               const int2* __restrict__ cw,
                                               const unsigned short* __restrict__ m,
                                               const float* __restrict__ dinv,
                                               const float* __restrict__ b2,
                                               float* __restrict__ out) {
    int wid = (blockIdx.x * blockDim.x + threadIdx.x) >> 6;
    int lane = threadIdx.x & 63;
    if (wid >= N_NODES) return;
    int beg = row_ptr[wid], end = row_ptr[wid + 1];
    float di = dinv[wid];
    float acc = di * di * bfs(m[(size_t)wid * 128 + lane]) + b2[lane];
    int e = beg;
    for (; e + 8 <= end; e += 8) {
        int2 c0 = cw[e + 0], c1 = cw[e + 1], c2 = cw[e + 2], c3 = cw[e + 3];
        int2 c4 = cw[e + 4], c5 = cw[e + 5], c6 = cw[e + 6], c7 = cw[e + 7];
        float v0 = bfs(m[(size_t)c0.x * 128 + lane]);
        float v1 = bfs(m[(size_t)c1.x * 128 + lane]);
        float v2 = bfs(m[(size_t)c2.x * 128 + lane]);
        float v3 = bfs(m[(size_t)c3.x * 128 + lane]);
        float v4 = bfs(m[(size_t)c4.x * 128 + lane]);
        float v5 = bfs(m[(size_t)c5.x * 128 + lane]);
        float v6 = bfs(m[(size_t)c6.x * 128 + lane]);
        float v7 = bfs(m[(size_t)c7.x * 128 + lane]);
        acc += __int_as_float(c0.y) * v0;
        acc += __int_as_float(c1.y) * v1;
        acc += __int_as_float(c2.y) * v2;
        acc += __int_as_float(c3.y) * v3;
        acc += __int_as_float(c4.y) * v4;
        acc += __int_as_float(c5.y) * v5;
        acc += __int_as_float(c6.y) * v6;
        acc += __int_as_float(c7.y) * v7;
    }
    for (; e < end; e++) {
        int2 c = cw[e];
        acc += __int_as_float(c.y) * bfs(m[(size_t)c.x * 128 + lane]);
    }
    out[(size_t)wid * D_OUT + lane] = acc;
}

// ---------------- launch ----------------

extern "C" void kernel_launch(void* const* d_in, const int* in_sizes, int n_in,
                              void* d_out, int out_size, void* d_ws, size_t ws_size,
                              hipStream_t stream) {
    const float* x  = (const float*)d_in[0];
    const int*   ei = (const int*)d_in[1];
    const float* W1 = (const float*)d_in[2];
    const float* b1 = (const float*)d_in[3];
    const float* W2 = (const float*)d_in[4];
    const float* b2 = (const float*)d_in[5];
    float* out = (float*)d_out;

    const int E = in_sizes[1] / 2;
    const int* src = ei;
    const int* dst = ei + E;

    // workspace layout — total 58,901,248 B (identical proven-good footprint to R4)
    char* ws = (char*)d_ws;
    int* cnt            = (int*)(ws + 0);          // 100096 ints (+bsum tail)
    int* bsum           = cnt + 100096;            // 391 ints
    int* row_ptr        = (int*)(ws + 402176);     // 100001 ints
    int2* cw            = (int2*)(ws + 802560);    // 800000 int2 (6.4 MB)
    float* dinv         = (float*)(ws + 7202560);  // 100096 f
    unsigned short* W1t = (unsigned short*)(ws + 7602944);   // 256*128 bf16
    unsigned short* W2t = (unsigned short*)(ws + 7668480);   // 64*256 bf16
    unsigned short* xb  = (unsigned short*)(ws + 7701248);   // N*128 bf16 (25.6 MB)
    unsigned short* aggb = (unsigned short*)(ws + 33301248); // N*128 bf16 (25.6 MB)
    // bucket scratch aliased into aggb's region (dead before k_pull1 writes aggb)
    int* bhist          = (int*)aggb;              // 196 ints
    int* bbase          = bhist + 256;             // 197 ints
    int* bcursor        = bhist + 512;             // 196 ints
    unsigned int* bin   = (unsigned int*)((char*)aggb + 4096);  // E uints (3.2 MB)

    const int NB = (N_NODES + 255) / 256;   // 391
    const int NBB = (E + 4095) / 4096;      // 196 edge blocks

    // prep: cvt_x | cvt_w1 | cvt_w2 | zero bhist
    k_prep<<<12693, 256, 0, stream>>>(x, (unsigned long long*)xb, W1, W1t, W2, W2t, bhist);

    // bucketed CSR build
    k_hist<<<NBB, 256, 0, stream>>>(dst, E, bhist);
    k_scanB<<<1, 256, 0, stream>>>(bhist, bbase, bcursor);
    k_bin<<<NBB, 256, 0, stream>>>(src, dst, E, bcursor, bin);
    k_cnt<<<NBUK, 256, 0, stream>>>(bin, bbase, cnt);
    k_scan_part<<<NB, 256, 0, stream>>>(cnt, row_ptr, bsum, dinv, N_NODES);
    k_scan_base<<<1, 512, 0, stream>>>(bsum, row_ptr, NB, N_NODES);
    k_scan_fin<<<NB, 256, 0, stream>>>(row_ptr, bsum, N_NODES);
    k_place<<<NBUK, 256, 0, stream>>>(bin, bbase, row_ptr, dinv, cw);

    // layer-1 pull (bf16 gather, 128 dims)
    k_pull1<<<(N_NODES * 64 + 255) / 256, 256, 0, stream>>>(row_ptr, cw,
                                                            (const unsigned int*)xb, dinv,
                                                            (unsigned int*)aggb);

    // fused MFMA GEMM chain -> m (bf16, in place over aggb)
    k_fused_mfma<<<N_NODES / TR, 256, 0, stream>>>(aggb, W1t, b1, W2t);

    // layer-2 pull (64 dims, bf16 gather) + bias
    k_pull2<<<(N_NODES * 64 + 255) / 256, 256, 0, stream>>>(row_ptr, cw, aggb, dinv, b2, out);
}

// Round 8
// 167.479 us; speedup vs baseline: 1.5703x; 1.2906x over previous
//
#include <hip/hip_runtime.h>
#include <hip/hip_bf16.h>

#define N_NODES 100000
#define D_IN 128
#define HID 256
#define D_OUT 64
#define TR 32
#define NBUK 196   // dst>>9 buckets of 512 nodes
#define BSH 9

typedef __attribute__((ext_vector_type(8))) short bf8;
typedef __attribute__((ext_vector_type(4))) float f4;

static __device__ __forceinline__ unsigned short f2bf(float f) {
    __hip_bfloat16 h = __float2bfloat16(f);
    return *reinterpret_cast<unsigned short*>(&h);
}
static __device__ __forceinline__ float bflo(unsigned int u) { return __uint_as_float(u << 16); }
static __device__ __forceinline__ float bfhi(unsigned int u) { return __uint_as_float(u & 0xffff0000u); }

// 8 bf16 (uint4) FMA into a[0..7]
static __device__ __forceinline__ void fma8(float* a, float w, uint4 u) {
    a[0] += w * bflo(u.x); a[1] += w * bfhi(u.x);
    a[2] += w * bflo(u.y); a[3] += w * bfhi(u.y);
    a[4] += w * bflo(u.z); a[5] += w * bfhi(u.z);
    a[6] += w * bflo(u.w); a[7] += w * bfhi(u.w);
}
// 4 bf16 (uint2) FMA into a[0..3]
static __device__ __forceinline__ void fma4(float* a, float w, uint2 u) {
    a[0] += w * bflo(u.x); a[1] += w * bfhi(u.x);
    a[2] += w * bflo(u.y); a[3] += w * bfhi(u.y);
}

// ---------------- fused prep: cvt_x | cvt_w1 | cvt_w2 | zero(bhist) ----------------

__global__ __launch_bounds__(256) void k_prep(const float* __restrict__ x,
                                              unsigned long long* __restrict__ xb,
                                              const float* __restrict__ W1,
                                              unsigned short* __restrict__ W1t,
                                              const float* __restrict__ W2,
                                              unsigned short* __restrict__ W2t,
                                              int* __restrict__ bhist) {
    int b = blockIdx.x, t = threadIdx.x;
    if (b < 12500) {
        int i = b * 256 + t;  // float4 index over x
        float4 v = ((const float4*)x)[i];
        unsigned long long o = (unsigned long long)f2bf(v.x) |
                               ((unsigned long long)f2bf(v.y) << 16) |
                               ((unsigned long long)f2bf(v.z) << 32) |
                               ((unsigned long long)f2bf(v.w) << 48);
        xb[i] = o;
    } else if (b < 12628) {
        int i = (b - 12500) * 256 + t;
        int n = i >> 7, k = i & 127;
        W1t[i] = f2bf(W1[k * HID + n]);
    } else if (b < 12692) {
        int i = (b - 12628) * 256 + t;
        int n = i >> 8, k = i & 255;
        W2t[i] = f2bf(W2[k * D_OUT + n]);
    } else {
        if (t < NBUK) bhist[t] = 0;
    }
}

// ---------------- bucketed CSR build ----------------

__global__ __launch_bounds__(256) void k_hist(const int* __restrict__ dst, int E,
                                              int* __restrict__ bhist) {
    __shared__ int h[NBUK];
    int t = threadIdx.x;
    if (t < NBUK) h[t] = 0;
    __syncthreads();
    int base = blockIdx.x * 4096;
    for (int j = 0; j < 16; j++) {
        int e = base + j * 256 + t;
        if (e < E) atomicAdd(&h[dst[e] >> BSH], 1);
    }
    __syncthreads();
    if (t < NBUK && h[t] > 0) atomicAdd(&bhist[t], h[t]);
}

__global__ __launch_bounds__(256) void k_scanB(const int* __restrict__ bhist,
                                               int* __restrict__ bbase,
                                               int* __restrict__ bcursor) {
    __shared__ int s[256];
    int t = threadIdx.x;
    int v = (t < NBUK) ? bhist[t] : 0;
    s[t] = v;
    __syncthreads();
    for (int off = 1; off < 256; off <<= 1) {
        int u = (t >= off) ? s[t - off] : 0;
        __syncthreads();
        s[t] += u;
        __syncthreads();
    }
    if (t < NBUK) {
        bbase[t] = s[t] - v;
        bcursor[t] = s[t] - v;
    }
    if (t == NBUK - 1) bbase[NBUK] = s[t];
}

// record = (dst&511)<<17 | src
__global__ __launch_bounds__(256) void k_bin(const int* __restrict__ src,
                                             const int* __restrict__ dst, int E,
                                             int* __restrict__ bcursor,
                                             unsigned int* __restrict__ bin) {
    __shared__ int histL[NBUK], baseL[NBUK], rankL[NBUK];
    int t = threadIdx.x;
    if (t < NBUK) {
        histL[t] = 0;
        rankL[t] = 0;
    }
    __syncthreads();
    int base = blockIdx.x * 4096;
    int ss[16], dd[16];
#pragma unroll
    for (int j = 0; j < 16; j++) {
        int e = base + j * 256 + t;
        if (e < E) {
            ss[j] = src[e];
            dd[j] = dst[e];
            atomicAdd(&histL[dd[j] >> BSH], 1);
        } else {
            dd[j] = -1;
        }
    }
    __syncthreads();
    if (t < NBUK && histL[t] > 0) baseL[t] = atomicAdd(&bcursor[t], histL[t]);
    __syncthreads();
#pragma unroll
    for (int j = 0; j < 16; j++) {
        if (dd[j] >= 0) {
            int bu = dd[j] >> BSH;
            int r = atomicAdd(&rankL[bu], 1);
            bin[baseL[bu] + r] = ((unsigned int)(dd[j] & 511) << 17) | (unsigned int)ss[j];
        }
    }
}

__global__ __launch_bounds__(256) void k_cnt(const unsigned int* __restrict__ bin,
                                             const int* __restrict__ bbase,
                                             int* __restrict__ cnt) {
    __shared__ int c[512];
    int b = blockIdx.x, t = threadIdx.x;
    c[t] = 0;
    c[t + 256] = 0;
    __syncthreads();
    int lo = bbase[b], hi = bbase[b + 1];
    for (int e = lo + t; e < hi; e += 256) atomicAdd(&c[bin[e] >> 17], 1);
    __syncthreads();
    int node0 = b << BSH;
    int nbn = N_NODES - node0;
    if (nbn > 512) nbn = 512;
    if (t < nbn) cnt[node0 + t] = c[t];
    if (t + 256 < nbn) cnt[node0 + t + 256] = c[t + 256];
}

__global__ __launch_bounds__(256) void k_scan_part(const int* __restrict__ cnt,
                                                   int* __restrict__ row_ptr,
                                                   int* __restrict__ bsum,
                                                   float* __restrict__ dinv, int n) {
    __shared__ int s[256];
    int t = threadIdx.x, i = blockIdx.x * 256 + t;
    int v = (i < n) ? cnt[i] : 0;
    s[t] = v;
    __syncthreads();
    for (int off = 1; off < 256; off <<= 1) {
        int u = (t >= off) ? s[t - off] : 0;
        __syncthreads();
        s[t] += u;
        __syncthreads();
    }
    if (i < n) {
        row_ptr[i] = s[t] - v;
        dinv[i] = rsqrtf((float)v + 1.0f);  // +1 self-loop
    }
    if (t == 255) bsum[blockIdx.x] = s[255];
}

__global__ __launch_bounds__(512) void k_scan_base(int* __restrict__ bsum,
                                                   int* __restrict__ row_ptr, int nb, int n) {
    __shared__ int s[512];
    int t = threadIdx.x;
    int v = (t < nb) ? bsum[t] : 0;
    s[t] = v;
    __syncthreads();
    for (int off = 1; off < 512; off <<= 1) {
        int u = (t >= off) ? s[t - off] : 0;
        __syncthreads();
        s[t] += u;
        __syncthreads();
    }
    if (t < nb) bsum[t] = s[t] - v;
    if (t == 511) row_ptr[n] = s[511];
}

__global__ void k_scan_fin(int* __restrict__ row_ptr, const int* __restrict__ bsum, int n) {
    int i = blockIdx.x * blockDim.x + threadIdx.x;
    if (i < n) row_ptr[i] += bsum[i >> 8];
}

__global__ __launch_bounds__(256) void k_place(const unsigned int* __restrict__ bin,
                                               const int* __restrict__ bbase,
                                               const int* __restrict__ row_ptr,
                                               const float* __restrict__ dinv,
                                               int2* __restrict__ cw) {
    __shared__ int cur[512];
    __shared__ float dl[512];
    int b = blockIdx.x, t = threadIdx.x;
    int node0 = b << BSH;
    int nbn = N_NODES - node0;
    if (nbn > 512) nbn = 512;
    if (t < nbn) {
        cur[t] = row_ptr[node0 + t];
        dl[t] = dinv[node0 + t];
    }
    if (t + 256 < nbn) {
        cur[t + 256] = row_ptr[node0 + t + 256];
        dl[t + 256] = dinv[node0 + t + 256];
    }
    __syncthreads();
    int lo = bbase[b], hi = bbase[b + 1];
    for (int e = lo + t; e < hi; e += 256) {
        unsigned int rec = bin[e];
        int s = rec & 0x1FFFF;
        int dloc = rec >> 17;
        int pos = atomicAdd(&cur[dloc], 1);
        int2 v;
        v.x = s;
        v.y = __float_as_int(dinv[s] * dl[dloc]);
        cw[pos] = v;
    }
}

// ---------------- layer-1 pull: 4 nodes/wave, 16 lanes/node, uint4 (16 B) loads ----------------
// xb row = 256 B = 16 uint4; lane l of group g covers uint4 chunk l of node wave*4+g

__global__ __launch_bounds__(256) void k_pull1(const int* __restrict__ row_ptr,
                                               const int2* __restrict__ cw,
                                               const uint4* __restrict__ xb4,
                                               const float* __restrict__ dinv,
                                               uint4* __restrict__ agg4) {
    int wave = (blockIdx.x * 256 + threadIdx.x) >> 6;
    int lane = threadIdx.x & 63;
    int g = lane >> 4, l = lane & 15;
    int node = wave * 4 + g;  // grid sized so node < N_NODES always
    int beg = row_ptr[node], end = row_ptr[node + 1];
    float di = dinv[node];
    float a[8] = {0, 0, 0, 0, 0, 0, 0, 0};
    fma8(a, di * di, xb4[(size_t)node * 16 + l]);
    int e = beg;
    for (; e + 4 <= end; e += 4) {
        int2 c0 = cw[e + 0], c1 = cw[e + 1], c2 = cw[e + 2], c3 = cw[e + 3];
        uint4 u0 = xb4[(size_t)c0.x * 16 + l];
        uint4 u1 = xb4[(size_t)c1.x * 16 + l];
        uint4 u2 = xb4[(size_t)c2.x * 16 + l];
        uint4 u3 = xb4[(size_t)c3.x * 16 + l];
        fma8(a, __int_as_float(c0.y), u0);
        fma8(a, __int_as_float(c1.y), u1);
        fma8(a, __int_as_float(c2.y), u2);
        fma8(a, __int_as_float(c3.y), u3);
    }
    for (; e < end; e++) {
        int2 c = cw[e];
        fma8(a, __int_as_float(c.y), xb4[(size_t)c.x * 16 + l]);
    }
    uint4 o;
    o.x = (unsigned int)f2bf(a[0]) | ((unsigned int)f2bf(a[1]) << 16);
    o.y = (unsigned int)f2bf(a[2]) | ((unsigned int)f2bf(a[3]) << 16);
    o.z = (unsigned int)f2bf(a[4]) | ((unsigned int)f2bf(a[5]) << 16);
    o.w = (unsigned int)f2bf(a[6]) | ((unsigned int)f2bf(a[7]) << 16);
    agg4[(size_t)node * 16 + l] = o;
}

// ---------------- fused GEMM chain (MFMA): m = relu(agg@W1+b1)@W2, bf16 out ----------------
// m (64 bf16/row) written IN PLACE into first half of each agg row (stride 128 ushorts).

__global__ __launch_bounds__(256) void k_fused_mfma(unsigned short* __restrict__ agg,
                                                    const unsigned short* __restrict__ W1t,
                                                    const float* __restrict__ b1,
                                                    const unsigned short* __restrict__ W2t) {
    __shared__ char sA[TR * D_IN * 2];  // 8 KB, row stride 256B
    __shared__ char sH[TR * HID * 2];   // 16 KB, row stride 512B
    int t = threadIdx.x, wave = t >> 6, lane = t & 63;
    int lr = lane & 15, lg = lane >> 4;
    size_t row0 = (size_t)blockIdx.x * TR;

    {
        const float4* g = (const float4*)(agg + row0 * D_IN);
#pragma unroll
        for (int c0 = 0; c0 < 2; c0++) {
            int c = c0 * 256 + t;
            int row = c >> 4;
            *(float4*)(sA + ((c * 16) ^ ((row & 7) << 4))) = g[c];
        }
    }
    __syncthreads();

    f4 acc1[4][2];
#pragma unroll
    for (int tt = 0; tt < 4; tt++)
#pragma unroll
        for (int h = 0; h < 2; h++) acc1[tt][h] = (f4){0.f, 0.f, 0.f, 0.f};

#pragma unroll
    for (int kk = 0; kk < 4; kk++) {
        bf8 a0 = *(const bf8*)(sA + ((lr * 256 + kk * 64 + lg * 16) ^ ((lr & 7) << 4)));
        bf8 a1 = *(const bf8*)(sA + (((16 + lr) * 256 + kk * 64 + lg * 16) ^ (((16 + lr) & 7) << 4)));
#pragma unroll
        for (int tt = 0; tt < 4; tt++) {
            bf8 b = *(const bf8*)(W1t + (size_t)(wave * 64 + tt * 16 + lr) * D_IN + kk * 32 + lg * 8);
            acc1[tt][0] = __builtin_amdgcn_mfma_f32_16x16x32_bf16(a0, b, acc1[tt][0], 0, 0, 0);
            acc1[tt][1] = __builtin_amdgcn_mfma_f32_16x16x32_bf16(a1, b, acc1[tt][1], 0, 0, 0);
        }
    }

#pragma unroll
    for (int tt = 0; tt < 4; tt++) {
        int colc = wave * 64 + tt * 16 + lr;
        float bias = b1[colc];
#pragma unroll
        for (int h = 0; h < 2; h++) {
#pragma unroll
            for (int ri = 0; ri < 4; ri++) {
                int row = h * 16 + lg * 4 + ri;
                float hv = acc1[tt][h][ri] + bias;
                hv = hv > 0.f ? hv : 0.f;
                *(unsigned short*)(sH + ((row * 512 + colc * 2) ^ ((row & 7) << 4))) = f2bf(hv);
            }
        }
    }
    __syncthreads();

    f4 acc2[2];
    acc2[0] = (f4){0.f, 0.f, 0.f, 0.f};
    acc2[1] = (f4){0.f, 0.f, 0.f, 0.f};
#pragma unroll
    for (int kk = 0; kk < 8; kk++) {
        bf8 a0 = *(const bf8*)(sH + ((lr * 512 + kk * 64 + lg * 16) ^ ((lr & 7) << 4)));
        bf8 a1 = *(const bf8*)(sH + (((16 + lr) * 512 + kk * 64 + lg * 16) ^ (((16 + lr) & 7) << 4)));
        bf8 b = *(const bf8*)(W2t + (size_t)(wave * 16 + lr) * HID + kk * 32 + lg * 8);
        acc2[0] = __builtin_amdgcn_mfma_f32_16x16x32_bf16(a0, b, acc2[0], 0, 0, 0);
        acc2[1] = __builtin_amdgcn_mfma_f32_16x16x32_bf16(a1, b, acc2[1], 0, 0, 0);
    }
    int colc = wave * 16 + lr;
#pragma unroll
    for (int h = 0; h < 2; h++)
#pragma unroll
        for (int ri = 0; ri < 4; ri++) {
            int row = h * 16 + lg * 4 + ri;
            agg[(row0 + row) * 128 + colc] = f2bf(acc2[h][ri]);
        }
}

// ---------------- layer-2 pull: 4 nodes/wave, 16 lanes/node, uint2 (8 B) loads ----------------
// m row = 64 bf16 = 128 B at stride 256 B (32 uint2); lane l covers uint2 chunk l

__global__ __launch_bounds__(256) void k_pull2(const int* __restrict__ row_ptr,
                                               const int2* __restrict__ cw,
                                               const uint2* __restrict__ m2,
                                               const float* __restrict__ dinv,
                                               const float* __restrict__ b2,
                                               float4* __restrict__ out4) {
    int wave = (blockIdx.x * 256 + threadIdx.x) >> 6;
    int lane = threadIdx.x & 63;
    int g = lane >> 4, l = lane & 15;
    int node = wave * 4 + g;  // < N_NODES by grid sizing
    int beg = row_ptr[node], end = row_ptr[node + 1];
    float di = dinv[node];
    float a[4] = {0, 0, 0, 0};
    fma4(a, di * di, m2[(size_t)node * 32 + l]);
    int e = beg;
    for (; e + 4 <= end; e += 4) {
        int2 c0 = cw[e + 0], c1 = cw[e + 1], c2 = cw[e + 2], c3 = cw[e + 3];
        uint2 u0 = m2[(size_t)c0.x * 32 + l];
        uint2 u1 = m2[(size_t)c1.x * 32 + l];
        uint2 u2 = m2[(size_t)c2.x * 32 + l];
        uint2 u3 = m2[(size_t)c3.x * 32 + l];
        fma4(a, __int_as_float(c0.y), u0);
        fma4(a, __int_as_float(c1.y), u1);
        fma4(a, __int_as_float(c2.y), u2);
        fma4(a, __int_as_float(c3.y), u3);
    }
    for (; e < end; e++) {
        int2 c = cw[e];
        fma4(a, __int_as_float(c.y), m2[(size_t)c.x * 32 + l]);
    }
    float4 bv = ((const float4*)b2)[l];
    float4 o;
    o.x = a[0] + bv.x;
    o.y = a[1] + bv.y;
    o.z = a[2] + bv.z;
    o.w = a[3] + bv.w;
    out4[(size_t)node * 16 + l] = o;
}

// ---------------- launch ----------------

extern "C" void kernel_launch(void* const* d_in, const int* in_sizes, int n_in,
                              void* d_out, int out_size, void* d_ws, size_t ws_size,
                              hipStream_t stream) {
    const float* x  = (const float*)d_in[0];
    const int*   ei = (const int*)d_in[1];
    const float* W1 = (const float*)d_in[2];
    const float* b1 = (const float*)d_in[3];
    const float* W2 = (const float*)d_in[4];
    const float* b2 = (const float*)d_in[5];
    float* out = (float*)d_out;

    const int E = in_sizes[1] / 2;
    const int* src = ei;
    const int* dst = ei + E;

    // workspace layout — total 58,901,248 B (identical proven-good footprint)
    char* ws = (char*)d_ws;
    int* cnt            = (int*)(ws + 0);          // 100096 ints (+bsum tail)
    int* bsum           = cnt + 100096;            // 391 ints
    int* row_ptr        = (int*)(ws + 402176);     // 100001 ints
    int2* cw            = (int2*)(ws + 802560);    // 800000 int2 (6.4 MB)
    float* dinv         = (float*)(ws + 7202560);  // 100096 f
    unsigned short* W1t = (unsigned short*)(ws + 7602944);   // 256*128 bf16
    unsigned short* W2t = (unsigned short*)(ws + 7668480);   // 64*256 bf16
    unsigned short* xb  = (unsigned short*)(ws + 7701248);   // N*128 bf16 (25.6 MB)
    unsigned short* aggb = (unsigned short*)(ws + 33301248); // N*128 bf16 (25.6 MB)
    // bucket scratch aliased into aggb's region (dead before k_pull1 writes aggb)
    int* bhist          = (int*)aggb;              // 196 ints
    int* bbase          = bhist + 256;             // 197 ints
    int* bcursor        = bhist + 512;             // 196 ints
    unsigned int* bin   = (unsigned int*)((char*)aggb + 4096);  // E uints (3.2 MB)

    const int NB = (N_NODES + 255) / 256;   // 391
    const int NBB = (E + 4095) / 4096;      // 196 edge blocks

    // prep: cvt_x | cvt_w1 | cvt_w2 | zero bhist
    k_prep<<<12693, 256, 0, stream>>>(x, (unsigned long long*)xb, W1, W1t, W2, W2t, bhist);

    // bucketed CSR build
    k_hist<<<NBB, 256, 0, stream>>>(dst, E, bhist);
    k_scanB<<<1, 256, 0, stream>>>(bhist, bbase, bcursor);
    k_bin<<<NBB, 256, 0, stream>>>(src, dst, E, bcursor, bin);
    k_cnt<<<NBUK, 256, 0, stream>>>(bin, bbase, cnt);
    k_scan_part<<<NB, 256, 0, stream>>>(cnt, row_ptr, bsum, dinv, N_NODES);
    k_scan_base<<<1, 512, 0, stream>>>(bsum, row_ptr, NB, N_NODES);
    k_scan_fin<<<NB, 256, 0, stream>>>(row_ptr, bsum, N_NODES);
    k_place<<<NBUK, 256, 0, stream>>>(bin, bbase, row_ptr, dinv, cw);

    // layer-1 pull: 4 nodes/wave × 4 waves/block = 16 nodes/block; 6250*16 = 100000 exact
    k_pull1<<<6250, 256, 0, stream>>>(row_ptr, cw, (const uint4*)xb, dinv, (uint4*)aggb);

    // fused MFMA GEMM chain -> m (bf16, in place over aggb)
    k_fused_mfma<<<N_NODES / TR, 256, 0, stream>>>(aggb, W1t, b1, W2t);

    // layer-2 pull: same geometry
    k_pull2<<<6250, 256, 0, stream>>>(row_ptr, cw, (const uint2*)aggb, dinv, b2, (float4*)out);
}

// Round 9
// 159.315 us; speedup vs baseline: 1.6508x; 1.0512x over previous
//
#include <hip/hip_runtime.h>
#include <hip/hip_bf16.h>

#define N_NODES 100000
#define D_IN 128
#define HID 256
#define D_OUT 64
#define TR 32
#define NBUK 196   // dst>>9 buckets of 512 nodes
#define BSH 9
#define MGRID 625  // persistent mfma grid: 625 blocks x 5 tiles = 3125

typedef __attribute__((ext_vector_type(8))) short bf8;
typedef __attribute__((ext_vector_type(4))) float f4;

static __device__ __forceinline__ unsigned short f2bf(float f) {
    __hip_bfloat16 h = __float2bfloat16(f);
    return *reinterpret_cast<unsigned short*>(&h);
}
static __device__ __forceinline__ float bflo(unsigned int u) { return __uint_as_float(u << 16); }
static __device__ __forceinline__ float bfhi(unsigned int u) { return __uint_as_float(u & 0xffff0000u); }

// 8 bf16 (uint4) FMA into a[0..7]
static __device__ __forceinline__ void fma8(float* a, float w, uint4 u) {
    a[0] += w * bflo(u.x); a[1] += w * bfhi(u.x);
    a[2] += w * bflo(u.y); a[3] += w * bfhi(u.y);
    a[4] += w * bflo(u.z); a[5] += w * bfhi(u.z);
    a[6] += w * bflo(u.w); a[7] += w * bfhi(u.w);
}
// 4 bf16 (uint2) FMA into a[0..3]
static __device__ __forceinline__ void fma4(float* a, float w, uint2 u) {
    a[0] += w * bflo(u.x); a[1] += w * bfhi(u.x);
    a[2] += w * bflo(u.y); a[3] += w * bfhi(u.y);
}

// ---------------- fused prep: cvt_x | cvt_w1 | cvt_w2 | zero(bhist) ----------------

__global__ __launch_bounds__(256) void k_prep(const float* __restrict__ x,
                                              unsigned long long* __restrict__ xb,
                                              const float* __restrict__ W1,
                                              unsigned short* __restrict__ W1t,
                                              const float* __restrict__ W2,
                                              unsigned short* __restrict__ W2t,
                                              int* __restrict__ bhist) {
    int b = blockIdx.x, t = threadIdx.x;
    if (b < 12500) {
        int i = b * 256 + t;  // float4 index over x
        float4 v = ((const float4*)x)[i];
        unsigned long long o = (unsigned long long)f2bf(v.x) |
                               ((unsigned long long)f2bf(v.y) << 16) |
                               ((unsigned long long)f2bf(v.z) << 32) |
                               ((unsigned long long)f2bf(v.w) << 48);
        xb[i] = o;
    } else if (b < 12628) {
        int i = (b - 12500) * 256 + t;
        int n = i >> 7, k = i & 127;
        W1t[i] = f2bf(W1[k * HID + n]);
    } else if (b < 12692) {
        int i = (b - 12628) * 256 + t;
        int n = i >> 8, k = i & 255;
        W2t[i] = f2bf(W2[k * D_OUT + n]);
    } else {
        if (t < NBUK) bhist[t] = 0;
    }
}

// ---------------- bucketed CSR build ----------------

__global__ __launch_bounds__(256) void k_hist(const int* __restrict__ dst, int E,
                                              int* __restrict__ bhist) {
    __shared__ int h[NBUK];
    int t = threadIdx.x;
    if (t < NBUK) h[t] = 0;
    __syncthreads();
    int base = blockIdx.x * 4096;
    for (int j = 0; j < 16; j++) {
        int e = base + j * 256 + t;
        if (e < E) atomicAdd(&h[dst[e] >> BSH], 1);
    }
    __syncthreads();
    if (t < NBUK && h[t] > 0) atomicAdd(&bhist[t], h[t]);
}

__global__ __launch_bounds__(256) void k_scanB(const int* __restrict__ bhist,
                                               int* __restrict__ bbase,
                                               int* __restrict__ bcursor) {
    __shared__ int s[256];
    int t = threadIdx.x;
    int v = (t < NBUK) ? bhist[t] : 0;
    s[t] = v;
    __syncthreads();
    for (int off = 1; off < 256; off <<= 1) {
        int u = (t >= off) ? s[t - off] : 0;
        __syncthreads();
        s[t] += u;
        __syncthreads();
    }
    if (t < NBUK) {
        bbase[t] = s[t] - v;
        bcursor[t] = s[t] - v;
    }
    if (t == NBUK - 1) bbase[NBUK] = s[t];
}

// record = (dst&511)<<17 | src
__global__ __launch_bounds__(256) void k_bin(const int* __restrict__ src,
                                             const int* __restrict__ dst, int E,
                                             int* __restrict__ bcursor,
                                             unsigned int* __restrict__ bin) {
    __shared__ int histL[NBUK], baseL[NBUK], rankL[NBUK];
    int t = threadIdx.x;
    if (t < NBUK) {
        histL[t] = 0;
        rankL[t] = 0;
    }
    __syncthreads();
    int base = blockIdx.x * 4096;
    int ss[16], dd[16];
#pragma unroll
    for (int j = 0; j < 16; j++) {
        int e = base + j * 256 + t;
        if (e < E) {
            ss[j] = src[e];
            dd[j] = dst[e];
            atomicAdd(&histL[dd[j] >> BSH], 1);
        } else {
            dd[j] = -1;
        }
    }
    __syncthreads();
    if (t < NBUK && histL[t] > 0) baseL[t] = atomicAdd(&bcursor[t], histL[t]);
    __syncthreads();
#pragma unroll
    for (int j = 0; j < 16; j++) {
        if (dd[j] >= 0) {
            int bu = dd[j] >> BSH;
            int r = atomicAdd(&rankL[bu], 1);
            bin[baseL[bu] + r] = ((unsigned int)(dd[j] & 511) << 17) | (unsigned int)ss[j];
        }
    }
}

__global__ __launch_bounds__(256) void k_cnt(const unsigned int* __restrict__ bin,
                                             const int* __restrict__ bbase,
                                             int* __restrict__ cnt) {
    __shared__ int c[512];
    int b = blockIdx.x, t = threadIdx.x;
    c[t] = 0;
    c[t + 256] = 0;
    __syncthreads();
    int lo = bbase[b], hi = bbase[b + 1];
    for (int e = lo + t; e < hi; e += 256) atomicAdd(&c[bin[e] >> 17], 1);
    __syncthreads();
    int node0 = b << BSH;
    int nbn = N_NODES - node0;
    if (nbn > 512) nbn = 512;
    if (t < nbn) cnt[node0 + t] = c[t];
    if (t + 256 < nbn) cnt[node0 + t + 256] = c[t + 256];
}

__global__ __launch_bounds__(256) void k_scan_part(const int* __restrict__ cnt,
                                                   int* __restrict__ row_ptr,
                                                   int* __restrict__ bsum,
                                                   float* __restrict__ dinv, int n) {
    __shared__ int s[256];
    int t = threadIdx.x, i = blockIdx.x * 256 + t;
    int v = (i < n) ? cnt[i] : 0;
    s[t] = v;
    __syncthreads();
    for (int off = 1; off < 256; off <<= 1) {
        int u = (t >= off) ? s[t - off] : 0;
        __syncthreads();
        s[t] += u;
        __syncthreads();
    }
    if (i < n) {
        row_ptr[i] = s[t] - v;
        dinv[i] = rsqrtf((float)v + 1.0f);  // +1 self-loop
    }
    if (t == 255) bsum[blockIdx.x] = s[255];
}

__global__ __launch_bounds__(512) void k_scan_base(int* __restrict__ bsum,
                                                   int* __restrict__ row_ptr, int nb, int n) {
    __shared__ int s[512];
    int t = threadIdx.x;
    int v = (t < nb) ? bsum[t] : 0;
    s[t] = v;
    __syncthreads();
    for (int off = 1; off < 512; off <<= 1) {
        int u = (t >= off) ? s[t - off] : 0;
        __syncthreads();
        s[t] += u;
        __syncthreads();
    }
    if (t < nb) bsum[t] = s[t] - v;
    if (t == 511) row_ptr[n] = s[511];
}

__global__ void k_scan_fin(int* __restrict__ row_ptr, const int* __restrict__ bsum, int n) {
    int i = blockIdx.x * blockDim.x + threadIdx.x;
    if (i < n) row_ptr[i] += bsum[i >> 8];
}

__global__ __launch_bounds__(256) void k_place(const unsigned int* __restrict__ bin,
                                               const int* __restrict__ bbase,
                                               const int* __restrict__ row_ptr,
                                               const float* __restrict__ dinv,
                                               int2* __restrict__ cw) {
    __shared__ int cur[512];
    __shared__ float dl[512];
    int b = blockIdx.x, t = threadIdx.x;
    int node0 = b << BSH;
    int nbn = N_NODES - node0;
    if (nbn > 512) nbn = 512;
    if (t < nbn) {
        cur[t] = row_ptr[node0 + t];
        dl[t] = dinv[node0 + t];
    }
    if (t + 256 < nbn) {
        cur[t + 256] = row_ptr[node0 + t + 256];
        dl[t + 256] = dinv[node0 + t + 256];
    }
    __syncthreads();
    int lo = bbase[b], hi = bbase[b + 1];
    for (int e = lo + t; e < hi; e += 256) {
        unsigned int rec = bin[e];
        int s = rec & 0x1FFFF;
        int dloc = rec >> 17;
        int pos = atomicAdd(&cur[dloc], 1);
        int2 v;
        v.x = s;
        v.y = __float_as_int(dinv[s] * dl[dloc]);
        cw[pos] = v;
    }
}

// ---------------- layer-1 pull: 4 nodes/wave, 16 lanes/node, uint4 (16 B) loads ----------------

__global__ __launch_bounds__(256) void k_pull1(const int* __restrict__ row_ptr,
                                               const int2* __restrict__ cw,
                                               const uint4* __restrict__ xb4,
                                               const float* __restrict__ dinv,
                                               uint4* __restrict__ agg4) {
    int wave = (blockIdx.x * 256 + threadIdx.x) >> 6;
    int lane = threadIdx.x & 63;
    int g = lane >> 4, l = lane & 15;
    int node = wave * 4 + g;  // grid sized so node < N_NODES always
    int beg = row_ptr[node], end = row_ptr[node + 1];
    float di = dinv[node];
    float a[8] = {0, 0, 0, 0, 0, 0, 0, 0};
    fma8(a, di * di, xb4[(size_t)node * 16 + l]);
    int e = beg;
    for (; e + 4 <= end; e += 4) {
        int2 c0 = cw[e + 0], c1 = cw[e + 1], c2 = cw[e + 2], c3 = cw[e + 3];
        uint4 u0 = xb4[(size_t)c0.x * 16 + l];
        uint4 u1 = xb4[(size_t)c1.x * 16 + l];
        uint4 u2 = xb4[(size_t)c2.x * 16 + l];
        uint4 u3 = xb4[(size_t)c3.x * 16 + l];
        fma8(a, __int_as_float(c0.y), u0);
        fma8(a, __int_as_float(c1.y), u1);
        fma8(a, __int_as_float(c2.y), u2);
        fma8(a, __int_as_float(c3.y), u3);
    }
    for (; e < end; e++) {
        int2 c = cw[e];
        fma8(a, __int_as_float(c.y), xb4[(size_t)c.x * 16 + l]);
    }
    uint4 o;
    o.x = (unsigned int)f2bf(a[0]) | ((unsigned int)f2bf(a[1]) << 16);
    o.y = (unsigned int)f2bf(a[2]) | ((unsigned int)f2bf(a[3]) << 16);
    o.z = (unsigned int)f2bf(a[4]) | ((unsigned int)f2bf(a[5]) << 16);
    o.w = (unsigned int)f2bf(a[6]) | ((unsigned int)f2bf(a[7]) << 16);
    agg4[(size_t)node * 16 + l] = o;
}

// ---------------- fused GEMM chain (MFMA, persistent): m = relu(agg@W1+b1)@W2 ----------------
// 625 blocks x 5 tiles. Weights hoisted to registers (loop-invariant). A read
// directly from global (L2-hot, no LDS staging). sH = LDS round-trip for the
// K=256 regroup. m (bf16) written in place over each tile's agg rows (all A
// reads of the tile complete before the post-barrier GEMM2/write phase).

__global__ __launch_bounds__(256) void k_fused_mfma(unsigned short* __restrict__ agg,
                                                    const unsigned short* __restrict__ W1t,
                                                    const float* __restrict__ b1,
                                                    const unsigned short* __restrict__ W2t) {
    __shared__ char sH[TR * HID * 2];   // 16 KB, row stride 512B
    int t = threadIdx.x, wave = t >> 6, lane = t & 63;
    int lr = lane & 15, lg = lane >> 4;

    // hoist weight fragments (96 VGPR, loop-invariant)
    bf8 w1f[4][4];  // [kk][tt]
#pragma unroll
    for (int kk = 0; kk < 4; kk++)
#pragma unroll
        for (int tt = 0; tt < 4; tt++)
            w1f[kk][tt] = *(const bf8*)(W1t + (size_t)(wave * 64 + tt * 16 + lr) * D_IN + kk * 32 + lg * 8);
    bf8 w2f[8];
#pragma unroll
    for (int kk = 0; kk < 8; kk++)
        w2f[kk] = *(const bf8*)(W2t + (size_t)(wave * 16 + lr) * HID + kk * 32 + lg * 8);
    float bias[4];
#pragma unroll
    for (int tt = 0; tt < 4; tt++) bias[tt] = b1[wave * 64 + tt * 16 + lr];

    for (int it = 0; it < 5; it++) {
        size_t row0 = ((size_t)blockIdx.x + (size_t)it * MGRID) * TR;

        // GEMM1: A direct from global (rows lr, 16+lr; k-slice kk*32+lg*8)
        f4 acc1[4][2];
#pragma unroll
        for (int tt = 0; tt < 4; tt++)
#pragma unroll
            for (int h = 0; h < 2; h++) acc1[tt][h] = (f4){0.f, 0.f, 0.f, 0.f};

#pragma unroll
        for (int kk = 0; kk < 4; kk++) {
            bf8 a0 = *(const bf8*)(agg + (row0 + lr) * 128 + kk * 32 + lg * 8);
            bf8 a1 = *(const bf8*)(agg + (row0 + 16 + lr) * 128 + kk * 32 + lg * 8);
#pragma unroll
            for (int tt = 0; tt < 4; tt++) {
                acc1[tt][0] = __builtin_amdgcn_mfma_f32_16x16x32_bf16(a0, w1f[kk][tt], acc1[tt][0], 0, 0, 0);
                acc1[tt][1] = __builtin_amdgcn_mfma_f32_16x16x32_bf16(a1, w1f[kk][tt], acc1[tt][1], 0, 0, 0);
            }
        }

        // epilogue 1: bias + relu + cvt bf16 -> sH (XOR swizzle byte ^= (row&7)<<4)
#pragma unroll
        for (int tt = 0; tt < 4; tt++) {
            int colc = wave * 64 + tt * 16 + lr;
#pragma unroll
            for (int h = 0; h < 2; h++) {
#pragma unroll
                for (int ri = 0; ri < 4; ri++) {
                    int row = h * 16 + lg * 4 + ri;
                    float hv = acc1[tt][h][ri] + bias[tt];
                    hv = hv > 0.f ? hv : 0.f;
                    *(unsigned short*)(sH + ((row * 512 + colc * 2) ^ ((row & 7) << 4))) = f2bf(hv);
                }
            }
        }
        __syncthreads();

        // GEMM2: K=256 from sH, B = hoisted w2f
        f4 acc2[2];
        acc2[0] = (f4){0.f, 0.f, 0.f, 0.f};
        acc2[1] = (f4){0.f, 0.f, 0.f, 0.f};
#pragma unroll
        for (int kk = 0; kk < 8; kk++) {
            bf8 a0 = *(const bf8*)(sH + ((lr * 512 + kk * 64 + lg * 16) ^ ((lr & 7) << 4)));
            bf8 a1 = *(const bf8*)(sH + (((16 + lr) * 512 + kk * 64 + lg * 16) ^ (((16 + lr) & 7) << 4)));
            acc2[0] = __builtin_amdgcn_mfma_f32_16x16x32_bf16(a0, w2f[kk], acc2[0], 0, 0, 0);
            acc2[1] = __builtin_amdgcn_mfma_f32_16x16x32_bf16(a1, w2f[kk], acc2[1], 0, 0, 0);
        }
        // write m (bf16) into first 64 ushorts of each owned agg row (stride 128)
        int colc = wave * 16 + lr;
#pragma unroll
        for (int h = 0; h < 2; h++)
#pragma unroll
            for (int ri = 0; ri < 4; ri++) {
                int row = h * 16 + lg * 4 + ri;
                agg[(row0 + row) * 128 + colc] = f2bf(acc2[h][ri]);
            }
        __syncthreads();  // protect sH before next tile's epilogue
    }
}

// ---------------- layer-2 pull: 4 nodes/wave, 16 lanes/node, uint2 (8 B) loads ----------------

__global__ __launch_bounds__(256) void k_pull2(const int* __restrict__ row_ptr,
                                               const int2* __restrict__ cw,
                                               const uint2* __restrict__ m2,
                                               const float* __restrict__ dinv,
                                               const float* __restrict__ b2,
                                               float4* __restrict__ out4) {
    int wave = (blockIdx.x * 256 + threadIdx.x) >> 6;
    int lane = threadIdx.x & 63;
    int g = lane >> 4, l = lane & 15;
    int node = wave * 4 + g;  // < N_NODES by grid sizing
    int beg = row_ptr[node], end = row_ptr[node + 1];
    float di = dinv[node];
    float a[4] = {0, 0, 0, 0};
    fma4(a, di * di, m2[(size_t)node * 32 + l]);
    int e = beg;
    for (; e + 4 <= end; e += 4) {
        int2 c0 = cw[e + 0], c1 = cw[e + 1], c2 = cw[e + 2], c3 = cw[e + 3];
        uint2 u0 = m2[(size_t)c0.x * 32 + l];
        uint2 u1 = m2[(size_t)c1.x * 32 + l];
        uint2 u2 = m2[(size_t)c2.x * 32 + l];
        uint2 u3 = m2[(size_t)c3.x * 32 + l];
        fma4(a, __int_as_float(c0.y), u0);
        fma4(a, __int_as_float(c1.y), u1);
        fma4(a, __int_as_float(c2.y), u2);
        fma4(a, __int_as_float(c3.y), u3);
    }
    for (; e < end; e++) {
        int2 c = cw[e];
        fma4(a, __int_as_float(c.y), m2[(size_t)c.x * 32 + l]);
    }
    float4 bv = ((const float4*)b2)[l];
    float4 o;
    o.x = a[0] + bv.x;
    o.y = a[1] + bv.y;
    o.z = a[2] + bv.z;
    o.w = a[3] + bv.w;
    out4[(size_t)node * 16 + l] = o;
}

// ---------------- launch ----------------

extern "C" void kernel_launch(void* const* d_in, const int* in_sizes, int n_in,
                              void* d_out, int out_size, void* d_ws, size_t ws_size,
                              hipStream_t stream) {
    const float* x  = (const float*)d_in[0];
    const int*   ei = (const int*)d_in[1];
    const float* W1 = (const float*)d_in[2];
    const float* b1 = (const float*)d_in[3];
    const float* W2 = (const float*)d_in[4];
    const float* b2 = (const float*)d_in[5];
    float* out = (float*)d_out;

    const int E = in_sizes[1] / 2;
    const int* src = ei;
    const int* dst = ei + E;

    // workspace layout — total 58,901,248 B (identical proven-good footprint)
    char* ws = (char*)d_ws;
    int* cnt            = (int*)(ws + 0);          // 100096 ints (+bsum tail)
    int* bsum           = cnt + 100096;            // 391 ints
    int* row_ptr        = (int*)(ws + 402176);     // 100001 ints
    int2* cw            = (int2*)(ws + 802560);    // 800000 int2 (6.4 MB)
    float* dinv         = (float*)(ws + 7202560);  // 100096 f
    unsigned short* W1t = (unsigned short*)(ws + 7602944);   // 256*128 bf16
    unsigned short* W2t = (unsigned short*)(ws + 7668480);   // 64*256 bf16
    unsigned short* xb  = (unsigned short*)(ws + 7701248);   // N*128 bf16 (25.6 MB)
    unsigned short* aggb = (unsigned short*)(ws + 33301248); // N*128 bf16 (25.6 MB)
    // bucket scratch aliased into aggb's region (dead before k_pull1 writes aggb)
    int* bhist          = (int*)aggb;              // 196 ints
    int* bbase          = bhist + 256;             // 197 ints
    int* bcursor        = bhist + 512;             // 196 ints
    unsigned int* bin   = (unsigned int*)((char*)aggb + 4096);  // E uints (3.2 MB)

    const int NB = (N_NODES + 255) / 256;   // 391
    const int NBB = (E + 4095) / 4096;      // 196 edge blocks

    // prep: cvt_x | cvt_w1 | cvt_w2 | zero bhist
    k_prep<<<12693, 256, 0, stream>>>(x, (unsigned long long*)xb, W1, W1t, W2, W2t, bhist);

    // bucketed CSR build
    k_hist<<<NBB, 256, 0, stream>>>(dst, E, bhist);
    k_scanB<<<1, 256, 0, stream>>>(bhist, bbase, bcursor);
    k_bin<<<NBB, 256, 0, stream>>>(src, dst, E, bcursor, bin);
    k_cnt<<<NBUK, 256, 0, stream>>>(bin, bbase, cnt);
    k_scan_part<<<NB, 256, 0, stream>>>(cnt, row_ptr, bsum, dinv, N_NODES);
    k_scan_base<<<1, 512, 0, stream>>>(bsum, row_ptr, NB, N_NODES);
    k_scan_fin<<<NB, 256, 0, stream>>>(row_ptr, bsum, N_NODES);
    k_place<<<NBUK, 256, 0, stream>>>(bin, bbase, row_ptr, dinv, cw);

    // layer-1 pull: 4 nodes/wave × 4 waves/block = 16 nodes/block; 6250*16 = 100000 exact
    k_pull1<<<6250, 256, 0, stream>>>(row_ptr, cw, (const uint4*)xb, dinv, (uint4*)aggb);

    // fused MFMA GEMM chain (persistent, weights in regs) -> m (bf16, in place)
    k_fused_mfma<<<MGRID, 256, 0, stream>>>(aggb, W1t, b1, W2t);

    // layer-2 pull: same geometry
    k_pull2<<<6250, 256, 0, stream>>>(row_ptr, cw, (const uint2*)aggb, dinv, b2, (float4*)out);
}